// Round 6
// baseline (112.328 us; speedup 1.0000x reference)
//
#include <hip/hip_runtime.h>

// Problem constants
#define BSZ 16
#define NN  128
#define HH  256
#define LLG 9
#define FFE 48   // edge feature dim (padded to 64 for MFMA K)

typedef float        f32x4 __attribute__((ext_vector_type(4)));
typedef _Float16     f16x8 __attribute__((ext_vector_type(8)));
typedef unsigned int u32x4 __attribute__((ext_vector_type(4)));

static __device__ __forceinline__ unsigned short f2h_bits(float x) {
    _Float16 h = (_Float16)x;   // RNE
    return __builtin_bit_cast(unsigned short, h);
}

static __device__ __forceinline__ float fast_silu(float x) {
    float e = __builtin_amdgcn_exp2f(x * -1.44269504088896341f);
    return x * __builtin_amdgcn_rcpf(1.0f + e);
}

// ---------------------------------------------------------------------------
// Kernel 1: weight transpose + f32->f16 convert.  (proven)
// ---------------------------------------------------------------------------
__global__ __launch_bounds__(256) void pre_w(
    const float* __restrict__ W1, const float* __restrict__ W2,
    unsigned short* __restrict__ W2T, unsigned short* __restrict__ WeT)
{
    int tid = blockIdx.x * 256 + threadIdx.x;   // grid 256 -> 65536 threads
    {
        int ho = tid >> 8, k = tid & 255;
        W2T[(ho << 8) + k] = f2h_bits(W2[(k << 8) + ho]);  // coalesced write
    }
    if (tid < 256 * 64) {
        int h = tid >> 6, f = tid & 63;
        WeT[(h << 6) + f] = (f < FFE) ? f2h_bits(W1[(521 + f) * HH + h])
                                      : (unsigned short)0;
    }
}

// ---------------------------------------------------------------------------
// Kernel 2: pj[b,r,h] = node@Wj ; base[b,r,h] = node@Wi + graph@Wg + b1 (proven)
// ---------------------------------------------------------------------------
__global__ __launch_bounds__(256) void pre_pjbase(
    const float* __restrict__ node, const float* __restrict__ graph,
    const float* __restrict__ W1, const float* __restrict__ b1,
    float* __restrict__ pj, float* __restrict__ base)
{
    __shared__ float nrow[4][HH];
    __shared__ float gsh[LLG];
    const int blk = blockIdx.x;
    const int b = blk >> 5;             // 32 row-groups of 4 per batch
    const int r0 = (blk & 31) << 2;
    const int h = threadIdx.x;

    for (int t = h; t < 4 * HH; t += 256) {
        int r = t >> 8, k = t & 255;
        nrow[r][k] = node[(((size_t)b * NN) + r0 + r) * HH + k];
    }
    if (h < LLG) gsh[h] = graph[b * LLG + h];
    __syncthreads();

    float accj[4] = {0,0,0,0};
    float acci[4] = {0,0,0,0};
    for (int k = 0; k < HH; ++k) {
        float wj = W1[k * HH + h];
        float wi = W1[(k + HH) * HH + h];
        #pragma unroll
        for (int r = 0; r < 4; ++r) {
            float nv = nrow[r][k];
            accj[r] = fmaf(nv, wj, accj[r]);
            acci[r] = fmaf(nv, wi, acci[r]);
        }
    }
    float accg = b1[h];
    #pragma unroll
    for (int l = 0; l < LLG; ++l)
        accg = fmaf(gsh[l], W1[(2 * HH + l) * HH + h], accg);

    #pragma unroll
    for (int r = 0; r < 4; ++r) {
        size_t off = (((size_t)b * NN) + r0 + r) * HH + h;
        pj[off]   = accj[r];
        base[off] = acci[r] + accg;
    }
}

// ---------------------------------------------------------------------------
// Kernel 3: fused main (round-5 structure). Changes this round:
//  (1) GEMM1 C-init = base + pj   (loads drain under staging barrier; -adds)
//  (2) GEMM2 C-init = b2          (-adds)
//  (3) explicit W2T prefetch rotation in the kk loop (hide L2 latency)
// ---------------------------------------------------------------------------
__global__ __launch_bounds__(512, 4) void fused_msg(
    const float* __restrict__ edge, const float* __restrict__ pj,
    const float* __restrict__ base, const unsigned short* __restrict__ W2T,
    const unsigned short* __restrict__ WeT, const float* __restrict__ b2,
    float* __restrict__ out)
{
    __shared__ unsigned char h1s[NN * HH * 2];   // 64 KB: h1[j][h] f16, swizzled
    __shared__ unsigned char efs[NN * 64 * 2];   // 16 KB: edge[j][f] f16, padded+swizzled
    const int tid  = threadIdx.x;
    const int w    = tid >> 6;         // wave 0..7
    const int lane = tid & 63;
    const int q    = lane >> 4;        // quad 0..3
    const int c    = lane & 15;
    const int bi   = blockIdx.x;       // b*128 + i
    const int b    = bi >> 7;

    const float* eb = edge + (size_t)bi * (NN * FFE);

    // ---- stage edge block -> f16 LDS, row-padded to 64 f16, XOR-swizzled ----
    #pragma unroll
    for (int p = 0; p < 3; ++p) {
        const int e4 = p * 512 + tid;            // float4 index, < 1536
        const int j  = e4 / 12;                  // 12 float4 per 48-float row
        const int f4 = e4 - j * 12;              // 0..11
        const f32x4 x = *reinterpret_cast<const f32x4*>(eb + (e4 << 2));
        unsigned int lo = __builtin_bit_cast(unsigned int,
                            __builtin_amdgcn_cvt_pkrtz(x[0], x[1]));
        unsigned int hi = __builtin_bit_cast(unsigned int,
                            __builtin_amdgcn_cvt_pkrtz(x[2], x[3]));
        const unsigned int off = (unsigned)(j << 7) +
            (((unsigned)(f4 << 3)) ^ ((unsigned)(j & 7) << 4));
        *reinterpret_cast<uint2*>(&efs[off]) = make_uint2(lo, hi);
    }
    {   // zero-fill padded f in [48,64)
        const int j = tid >> 2, g = tid & 3;
        const unsigned int off = (unsigned)(j << 7) +
            (((unsigned)(96 + (g << 3))) ^ ((unsigned)(j & 7) << 4));
        *reinterpret_cast<uint2*>(&efs[off]) = make_uint2(0u, 0u);
    }

    // ---- GEMM1 accumulator C-init: base[i][h] + pj[j][h] ----
    // These 18 global loads issue now and are drained by the barrier's
    // vmcnt(0), i.e. their latency hides under the staging writes above.
    f32x4 acc1[2][8];
    #pragma unroll
    for (int mt = 0; mt < 2; ++mt) {
        const int h0 = (w << 5) + (mt << 4) + (q << 2);
        const f32x4 bb = *reinterpret_cast<const f32x4*>(
            base + ((size_t)bi << 8) + h0);
        #pragma unroll
        for (int nt = 0; nt < 8; ++nt) {
            const int jc = (nt << 4) + c;
            const f32x4 pjv = *reinterpret_cast<const f32x4*>(
                pj + (((size_t)b << 7) + jc) * HH + h0);
            acc1[mt][nt] = bb + pjv;
        }
    }
    __syncthreads();

    // ------------------ GEMM1: D1[h(32), j(128)] ------------------
    #pragma unroll
    for (int kk = 0; kk < 2; ++kk) {
        const int koff = (kk << 5) + (q << 3);   // f16-units f offset
        const int fb   = koff << 1;              // byte offset in efs row
        f16x8 af[2];
        #pragma unroll
        for (int mt = 0; mt < 2; ++mt) {
            const int row = (w << 5) + (mt << 4) + c;       // h
            af[mt] = *reinterpret_cast<const f16x8*>(WeT + (row << 6) + koff);
        }
        #pragma unroll
        for (int nt = 0; nt < 8; ++nt) {
            const int j = (nt << 4) + c;
            const f16x8 bf = *reinterpret_cast<const f16x8*>(
                &efs[(unsigned)(j << 7) +
                     (((unsigned)fb) ^ ((unsigned)(j & 7) << 4))]);
            #pragma unroll
            for (int mt = 0; mt < 2; ++mt)
                acc1[mt][nt] = __builtin_amdgcn_mfma_f32_16x16x32_f16(
                    af[mt], bf, acc1[mt][nt], 0, 0, 0);
        }
    }

    // epilogue 1: silu -> f16 -> h1s (swizzle: byte ^= (j&7)<<4); adds already in
    #pragma unroll
    for (int mt = 0; mt < 2; ++mt) {
        const int h0 = (w << 5) + (mt << 4) + (q << 2);
        #pragma unroll
        for (int nt = 0; nt < 8; ++nt) {
            const int jc = (nt << 4) + c;
            float s0 = fast_silu(acc1[mt][nt][0]);
            float s1 = fast_silu(acc1[mt][nt][1]);
            float s2 = fast_silu(acc1[mt][nt][2]);
            float s3 = fast_silu(acc1[mt][nt][3]);
            unsigned int lo = __builtin_bit_cast(unsigned int,
                                __builtin_amdgcn_cvt_pkrtz(s0, s1));
            unsigned int hi = __builtin_bit_cast(unsigned int,
                                __builtin_amdgcn_cvt_pkrtz(s2, s3));
            const unsigned int off = (unsigned)(jc << 9) +
                (((unsigned)(h0 << 1)) ^ ((unsigned)(jc & 7) << 4));
            *reinterpret_cast<uint2*>(&h1s[off]) = make_uint2(lo, hi);
        }
    }
    __syncthreads();

    // ------------------ GEMM2: D2[jc(128), ho(32)] ------------------
    float b2v[2];
    #pragma unroll
    for (int nt = 0; nt < 2; ++nt) b2v[nt] = b2[(w << 5) + (nt << 4) + c];

    f32x4 acc2[8][2];
    #pragma unroll
    for (int mt = 0; mt < 8; ++mt)
        #pragma unroll
        for (int nt = 0; nt < 2; ++nt)
            acc2[mt][nt] = f32x4{b2v[nt], b2v[nt], b2v[nt], b2v[nt]};

    const int ho0 = (w << 5) + c;            // nt=0 column
    const int ho1 = ho0 + 16;                // nt=1 column
    const unsigned short* wp0 = W2T + (ho0 << 8) + (q << 3);
    const unsigned short* wp1 = W2T + (ho1 << 8) + (q << 3);

    f16x8 bw0 = *reinterpret_cast<const f16x8*>(wp0);
    f16x8 bw1 = *reinterpret_cast<const f16x8*>(wp1);

    #pragma unroll 2
    for (int kk = 0; kk < 8; ++kk) {
        // prefetch next kk's W2T fragments (wraps at kk=7; harmless in-bounds)
        const int nk = (kk + 1) & 7;
        const f16x8 nb0 = *reinterpret_cast<const f16x8*>(wp0 + (nk << 5));
        const f16x8 nb1 = *reinterpret_cast<const f16x8*>(wp1 + (nk << 5));

        const int kb = (kk << 6) + (q << 4);     // byte offset of k-slice
        #pragma unroll
        for (int g = 0; g < 2; ++g) {
            f16x8 a2[4];
            #pragma unroll
            for (int m = 0; m < 4; ++m) {
                const int jc = ((g << 2) + m) * 16 + c;
                const unsigned int off = (unsigned)(jc << 9) +
                    (((unsigned)kb) ^ ((unsigned)(jc & 7) << 4));
                a2[m] = *reinterpret_cast<const f16x8*>(&h1s[off]);
            }
            #pragma unroll
            for (int m = 0; m < 4; ++m) {
                acc2[(g << 2) + m][0] = __builtin_amdgcn_mfma_f32_16x16x32_f16(
                    a2[m], bw0, acc2[(g << 2) + m][0], 0, 0, 0);
                acc2[(g << 2) + m][1] = __builtin_amdgcn_mfma_f32_16x16x32_f16(
                    a2[m], bw1, acc2[(g << 2) + m][1], 0, 0, 0);
            }
        }
        bw0 = nb0; bw1 = nb1;
    }

    // epilogue 2: silu + j-sum (b2 already in), butterfly across quads, store
    float s[2] = {0.f, 0.f};
    #pragma unroll
    for (int nt = 0; nt < 2; ++nt)
        #pragma unroll
        for (int mt = 0; mt < 8; ++mt)
            #pragma unroll
            for (int r = 0; r < 4; ++r)
                s[nt] += fast_silu(acc2[mt][nt][r]);

    #pragma unroll
    for (int nt = 0; nt < 2; ++nt) {
        s[nt] += __shfl_xor(s[nt], 16);
        s[nt] += __shfl_xor(s[nt], 32);
    }
    if (q < 2)
        out[((size_t)bi << 8) + (w << 5) + (q << 4) + c] = s[q] * 0.0078125f;
}

// ---------------------------------------------------------------------------
extern "C" void kernel_launch(void* const* d_in, const int* in_sizes, int n_in,
                              void* d_out, int out_size, void* d_ws, size_t ws_size,
                              hipStream_t stream)
{
    const float* node  = (const float*)d_in[0];
    const float* edge  = (const float*)d_in[1];
    const float* graph = (const float*)d_in[2];
    const float* W1    = (const float*)d_in[3];
    const float* b1    = (const float*)d_in[4];
    const float* W2    = (const float*)d_in[5];
    const float* b2    = (const float*)d_in[6];
    float* out = (float*)d_out;

    char* ws = (char*)d_ws;
    unsigned short* W2T = (unsigned short*)ws;              // 131072 B
    unsigned short* WeT = (unsigned short*)(ws + 131072);   //  32768 B
    float* pj   = (float*)(ws + 163840);                    // 2 MB
    float* base = (float*)(ws + 163840 + 2097152);          // 2 MB

    pre_w     <<<256, 256, 0, stream>>>(W1, W2, W2T, WeT);
    pre_pjbase<<<512, 256, 0, stream>>>(node, graph, W1, b1, pj, base);
    fused_msg <<<BSZ * NN, 512, 0, stream>>>(edge, pj, base, W2T, WeT, b2, out);
}